// Round 10
// baseline (131.594 us; speedup 1.0000x reference)
//
#include <hip/hip_runtime.h>
#include <hip/hip_bf16.h>
#include <stdint.h>

// Conv2d: x[128][256][256] (f32), w[256][128][3][3] (f32), bias[256] (f32)
// out[256][256][256] (f32).  pad=1, stride=1.
// bf16 MFMA implicit GEMM: M=COUT=256, N=65536 pixels, K=9 taps x 128 ch = 1152.
//   ws: x_p bf16 [258][258][128] (padded, channel-innermost), W_pk bf16 [9][256][128].
//
// R12 (post-mortem R7..R11: five schedule probes all converge at 44-45us. Refit:
// loop = 4450 cyc/tile vs LDS-PORT demand 2816 (reads 192xb128@12cyc + 512 wr)
// > MFMA 2483. The port is per-CU shared -> R9's 2-block null; traffic is
// schedule-invariant -> R11's prefetch null. Port traffic = sum(Mw+Nw)*BK*2B:
// the ONLY lever is wave shape. 8 waves of 128x64 = 1536 units; 4 waves of
// 128x128 = 1024 -> port 2048 < MFMA 2483 = clean MFMA pole):
//   - 4 waves (256 thr), wave tile 128x128, acc[8][8] = 256 VGPR, 1 wave/SIMD
//     (full 512-reg file; ~410 total, under the 450 no-spill line, m08).
//   - Pure ILP tile: issue all 32 frag ds_reads + 16 staging gloads up front,
//     then 128 MFMAs; compiler's counted lgkm waits overlap MFMA-ks0 with
//     ks1-read streaming. Stage gets the full ~2800-cyc tile of slack ->
//     plain __syncthreads() per tile (vmcnt(0) drain is free now); ALL manual
//     waitcnt asm removed (rule-18-safe).
//   - Same BM=BN=256, BK=64, 18 tiles, same LDS layout + octet XOR swizzle
//     triple, same staging formulas (rows/instr now 32), same XCD swizzle.
// Per-acc-element K-order identical -> bit-identical output expected.

#define CIN   128
#define COUT  256
#define HH    256
#define WW    256
#define HP    258
#define WP    258
#define XP_ELEMS (HP * WP * CIN)   // 8,520,192 bf16 elements

typedef __attribute__((ext_vector_type(8))) __bf16 bf16x8;
typedef __attribute__((ext_vector_type(4))) float  floatx4;
typedef __attribute__((ext_vector_type(8))) short  short8;

#define AS1 __attribute__((address_space(1)))
#define AS3 __attribute__((address_space(3)))

// ---------------- fused prep: xpose_pad | wpack | zero_border ----------------
__global__ __launch_bounds__(256) void prep(const float* __restrict__ x,
                                            const float* __restrict__ w,
                                            unsigned short* __restrict__ xp,
                                            unsigned short* __restrict__ wpk) {
    __shared__ __align__(16) unsigned short tile[64][136];  // xpose region only
    const int bid = blockIdx.x;
    const int t   = threadIdx.x;
    if (bid < 1024) {
        // transpose+cast x[c][h][w] -> x_p[h+1][w+1][c]
        int h  = bid >> 2;
        int w0 = (bid & 3) << 6;
        int wl = t & 63, icq = t >> 6;
        const float* src = x + h * WW + w0 + wl;
#pragma unroll
        for (int icb = 0; icb < 32; ++icb) {
            int ic = icb * 4 + icq;
            __hip_bfloat16 b = __float2bfloat16(src[ic * (HH * WW)]);
            tile[wl][ic] = __builtin_bit_cast(unsigned short, b);
        }
        __syncthreads();
        int wl2 = t >> 2, q = t & 3;    // 64 rows x 4 chunks of 64B
        const short8* s8 = (const short8*)&tile[wl2][q * 32];
        short8* d8 = (short8*)(xp + ((size_t)(h + 1) * WP + (w0 + 1) + wl2) * CIN + q * 32);
#pragma unroll
        for (int i = 0; i < 4; ++i) d8[i] = s8[i];
    } else if (bid < 2176) {
        // pack weights -> bf16 W_pk[kk][o][ic]
        int idx = (bid - 1024) * 256 + t;           // 0..294911
        int kk  = idx >> 15;
        int rem = idx & 32767;                      // o*128 + ic
        __hip_bfloat16 b = __float2bfloat16(w[rem * 9 + kk]);
        wpk[idx] = __builtin_bit_cast(unsigned short, b);
    } else {
        // zero the padded border: 1028 px x 16 octets, short8 stores
        int cid = (bid - 2176) * 256 + t;           // 0..16447
        if (cid < 16448) {
            int p = cid >> 4, oct = cid & 15;
            int hp, wp;
            if (p < 258)      { hp = 0;   wp = p; }
            else if (p < 516) { hp = 257; wp = p - 258; }
            else { int s = p - 516; hp = 1 + (s >> 1); wp = (s & 1) * 257; }
            short8 z = {0, 0, 0, 0, 0, 0, 0, 0};
            *(short8*)(xp + ((size_t)hp * WP + wp) * CIN + oct * 8) = z;
        }
    }
}

// ---------------- main: 256(M) x 256(pixels of row h), 4 waves of 128x128, 18 K-tiles ----------------
// Per buffer (32768 shorts = 64KB): A[256 o][64 ch] at 0, B[256 px][64 ch] at 16384.
// Swizzle: physical octet = logical octet ^ (row & 7)  (octet = 16 B).
//   stage: lane writes LDS linearly (32 rows/instr, row t>>3, slot t&7);
//          fetches pre-swizzled global octet (t&7)^((t>>3)&7).
//   read : frag (row, logical oct o) at shorts row*64 + ((o ^ (row&7))<<3).
__global__ __launch_bounds__(256, 1) void conv_mfma(
    const unsigned short* __restrict__ xp,   // [258][258][128] bf16
    const unsigned short* __restrict__ wpk,  // [9][256][128]   bf16
    const float* __restrict__ bias,          // [256] f32
    float* __restrict__ out) {               // [256][65536] f32
    __shared__ __align__(16) unsigned short x_lds[2 * 32768];   // 131,072 B

    const int tid  = threadIdx.x;            // 0..255
    const int lane = tid & 63;
    const int wv   = tid >> 6;               // 0..3
    const int l15  = lane & 15;
    const int lg   = lane >> 4;              // 0..3
    const int wave_m = (wv >> 1) << 7;       // 0 or 128
    const int wave_n = (wv & 1) << 7;        // 0 or 128

    // XCD swizzle (bijective, 256 % 8 == 0): XCD k gets rows [k*32, k*32+32).
    const int orig = blockIdx.x;
    const int h    = ((orig & 7) << 5) | (orig >> 3);

    // Staging per-thread source offset: row t>>3 (32 rows/instr), pre-swizzled octet.
    const int soff = (tid >> 3) * CIN + ((((tid & 7) ^ ((tid >> 3) & 7))) << 3);
    // Per-thread swizzled read octet (shorts); ks=1 flips bit2 (^32 shorts).
    const int aoct = (lg ^ (l15 & 7)) << 3;

    // One staging load: 256 thr x 16B = 4KB = 32 rows of 128B.
#define GLD(dst_, src_) \
    __builtin_amdgcn_global_load_lds((const AS1 void*)(src_), \
        (AS3 void*)((dst_) + tid * 8), 16, 0, 0)
#define LDA(Ab_, mb_, kx_) \
    (*(const bf16x8*)((Ab_) + (((mb_) + l15) << 6) + (aoct ^ (kx_))))
#define LDB(Ab_, nb2_, kx_) \
    (*(const bf16x8*)((Ab_) + 16384 + (((nb2_) + l15) << 6) + (aoct ^ (kx_))))

    auto stage = [&](int buf, int kk, int kh, int kw, int hf) {
        unsigned short* nb = x_lds + buf * 32768;
        const unsigned short* asrc = wpk + (size_t)kk * (COUT * CIN) + hf * 64 + soff;
        const unsigned short* bsrc = xp + ((size_t)(h + kh) * WP + kw) * CIN + hf * 64 + soff;
#pragma unroll
        for (int i = 0; i < 8; ++i) GLD(nb + i * 2048, asrc + i * 32 * CIN);
#pragma unroll
        for (int i = 0; i < 8; ++i) GLD(nb + 16384 + i * 2048, bsrc + i * 32 * CIN);
    };

    floatx4 acc[8][8];
#pragma unroll
    for (int fi = 0; fi < 8; ++fi)
#pragma unroll
        for (int fj = 0; fj < 8; ++fj) {
            floatx4 z = {0.f, 0.f, 0.f, 0.f};
            acc[fi][fj] = z;
        }

    // Prologue: stage tile 0 into buffer 0; __syncthreads drains vmcnt(0).
    stage(0, 0, 0, 0, 0);
    __syncthreads();

#pragma unroll
    for (int t2 = 0; t2 < 18; ++t2) {        // K-tile = (kk, ch-half)
        const int cur = t2 & 1;
        const unsigned short* Ab = x_lds + cur * 32768;

        // ks0 fragment reads (oldest lgkm -> MFMA ks0 can start while ks1 streams)
        bf16x8 a0[8], b0[8], a1[8], b1[8];
#pragma unroll
        for (int fj = 0; fj < 8; ++fj) b0[fj] = LDB(Ab, wave_n + fj * 16, 0);
#pragma unroll
        for (int fi = 0; fi < 8; ++fi) a0[fi] = LDA(Ab, wave_m + fi * 16, 0);

        // next tile's stage: 16 gloads get the whole ~2800-cyc tile of slack;
        // the end-of-tile __syncthreads drain finds them landed.
        if (t2 < 17) {
            const int tn  = t2 + 1;
            const int kkn = tn >> 1, hfn = tn & 1;
            const int khn = kkn / 3, kwn = kkn - khn * 3;
            stage(cur ^ 1, kkn, khn, kwn, hfn);
        }

        // ks1 fragment reads (issued before MFMA for ILP; consumed later)
#pragma unroll
        for (int fj = 0; fj < 8; ++fj) b1[fj] = LDB(Ab, wave_n + fj * 16, 32);
#pragma unroll
        for (int fi = 0; fi < 8; ++fi) a1[fi] = LDA(Ab, wave_m + fi * 16, 32);

        __builtin_amdgcn_s_setprio(1);
#pragma unroll
        for (int fi = 0; fi < 8; ++fi)
#pragma unroll
            for (int fj = 0; fj < 8; ++fj)
                acc[fi][fj] = __builtin_amdgcn_mfma_f32_16x16x32_bf16(
                    a0[fi], b0[fj], acc[fi][fj], 0, 0, 0);
#pragma unroll
        for (int fi = 0; fi < 8; ++fi)
#pragma unroll
            for (int fj = 0; fj < 8; ++fj)
                acc[fi][fj] = __builtin_amdgcn_mfma_f32_16x16x32_bf16(
                    a1[fi], b1[fj], acc[fi][fj], 0, 0, 0);
        __builtin_amdgcn_s_setprio(0);

        __syncthreads();   // vmcnt(0)+lgkmcnt(0)+barrier: buffer swap guarded
    }
#undef GLD
#undef LDA
#undef LDB

    // Epilogue: D row=(lane>>4)*4+reg (within 16), col=l15; add bias, store f32.
    const int nbase = h * WW + wave_n + l15;
#pragma unroll
    for (int fi = 0; fi < 8; ++fi) {
        int mrow = wave_m + fi * 16 + lg * 4;
#pragma unroll
        for (int r = 0; r < 4; ++r) {
            float bv = bias[mrow + r];
#pragma unroll
            for (int fj = 0; fj < 8; ++fj)
                out[(size_t)(mrow + r) * (HH * WW) + nbase + fj * 16] = acc[fi][fj][r] + bv;
        }
    }
}

extern "C" void kernel_launch(void* const* d_in, const int* in_sizes, int n_in,
                              void* d_out, int out_size, void* d_ws, size_t ws_size,
                              hipStream_t stream) {
    (void)in_sizes; (void)n_in; (void)out_size; (void)ws_size;
    const float* x    = (const float*)d_in[0];   // 128*256*256
    const float* w    = (const float*)d_in[1];   // 256*128*3*3
    const float* bias = (const float*)d_in[2];   // 256
    float* out = (float*)d_out;

    unsigned short* xp  = (unsigned short*)d_ws;            // bf16 [258][258][128]
    unsigned short* wpk = xp + XP_ELEMS;                    // bf16 [9][256][128]

    prep<<<dim3(2241), dim3(256), 0, stream>>>(x, w, xp, wpk);
    conv_mfma<<<dim3(256), dim3(256), 0, stream>>>(xp, wpk, bias, out);
}